// Round 9
// baseline (1298.768 us; speedup 1.0000x reference)
//
#include <hip/hip_runtime.h>

// BinarizedLinear: act[d,o] = sum_i W[d,o,i] * x[d,i];  out[d,o] = act > bias[d,o]
// W: [D][OUT][IN] fp32 of 0/1   (1.074 GB -- the whole cost; read once, coalesced)
// x: [D][IN] bool               (byte / int32 / float32 storage -- detected on device)
// bias: [D][OUT] fp32
// out: [D][OUT] as float 1.0/0.0 (reference returns bool)
//
// Round-9 = Round-4 front-issue structure with ONE variable changed: plain
// (L2-allocating) loads instead of nontemporal. Single-variable test of
// whether the nt no-allocate path degrades streaming-read efficiency.
// Sums are exact small integers in fp32 -> reduction order is bit-exact.

#define NDIR 64
#define NOUT 2048
#define NIN  2048

typedef float f4 __attribute__((ext_vector_type(4)));

__global__ __launch_bounds__(256) void binlin_kernel(
    const float* __restrict__ W,
    const unsigned char* __restrict__ X,
    const float* __restrict__ B,
    float* __restrict__ out)
{
    const int lane = threadIdx.x & 63;
    const int wave = threadIdx.x >> 6;                 // 4 waves/block, 1 row/wave
    const int row  = blockIdx.x * 4 + wave;            // [0, NDIR*NOUT)
    const int d    = row >> 11;                        // row / NOUT  (OUT = 2048)

    // --- storage-format probe for X (deterministic, wave-uniform) ---
    // float32: some word == 0x3F800000 (absent w.p. 2^-64).
    // bool bytes: some word > 1 (absent w.p. 8^-64).  int32: all words in {0,1}.
    const unsigned int probe = ((const unsigned int*)X)[lane];   // 256 B, in-bounds in all layouts
    const bool x_is_float = (__ballot(probe == 0x3F800000u) != 0ull);
    const bool x_is_bytes = !x_is_float && (__ballot(probe > 1u) != 0ull);

    const f4* w4 = (const f4*)(W + (size_t)row * NIN); // 8 KB row, lane-coalesced float4

    // Issue ALL weight loads first: 8 x global_load_dwordx4, 8 KB in flight.
    f4 w[8];
    #pragma unroll
    for (int j = 0; j < 8; ++j)
        w[j] = w4[j * 64 + lane];

    // Per-lane gate nibble for each float4 (x is L2/L3-hot: reused by 2048 rows).
    unsigned int g[8];
    if (x_is_float) {
        const f4* xf = (const f4*)X + (size_t)d * (NIN / 4);
        #pragma unroll
        for (int j = 0; j < 8; ++j) {
            const f4 xv = xf[j * 64 + lane];
            g[j] = (unsigned)(xv.x != 0.0f)        | ((unsigned)(xv.y != 0.0f) << 1)
                 | ((unsigned)(xv.z != 0.0f) << 2) | ((unsigned)(xv.w != 0.0f) << 3);
        }
    } else if (x_is_bytes) {
        const unsigned int* x4 = (const unsigned int*)(X + (size_t)d * NIN);
        #pragma unroll
        for (int j = 0; j < 8; ++j) {
            const unsigned int xb = x4[j * 64 + lane];   // 4 bool bytes
            g[j] = ((xb & 0x000000ffu) ? 1u : 0u) | ((xb & 0x0000ff00u) ? 2u : 0u)
                 | ((xb & 0x00ff0000u) ? 4u : 0u) | ((xb & 0xff000000u) ? 8u : 0u);
        }
    } else {
        const int* xi = (const int*)X + (size_t)d * NIN;
        #pragma unroll
        for (int j = 0; j < 8; ++j) {
            const int i4 = (j * 64 + lane) * 4;
            g[j] = (xi[i4+0] ? 1u : 0u) | (xi[i4+1] ? 2u : 0u)
                 | (xi[i4+2] ? 4u : 0u) | (xi[i4+3] ? 8u : 0u);
        }
    }

    float acc = 0.0f;
    #pragma unroll
    for (int j = 0; j < 8; ++j) {
        acc += (g[j] & 1u) ? w[j].x : 0.0f;
        acc += (g[j] & 2u) ? w[j].y : 0.0f;
        acc += (g[j] & 4u) ? w[j].z : 0.0f;
        acc += (g[j] & 8u) ? w[j].w : 0.0f;
    }

    // wave-64 reduction; sums are exact small integers in fp32 -> order-independent
    #pragma unroll
    for (int off = 32; off > 0; off >>= 1)
        acc += __shfl_down(acc, off, 64);

    if (lane == 0)
        out[row] = (acc > B[row]) ? 1.0f : 0.0f;
}

extern "C" void kernel_launch(void* const* d_in, const int* in_sizes, int n_in,
                              void* d_out, int out_size, void* d_ws, size_t ws_size,
                              hipStream_t stream) {
    const float*         W = (const float*)d_in[0];
    const unsigned char* X = (const unsigned char*)d_in[1];
    const float*         B = (const float*)d_in[2];
    float*               O = (float*)d_out;

    const int rows = NDIR * NOUT;                      // 131072
    binlin_kernel<<<dim3(rows / 4), dim3(256), 0, stream>>>(W, X, B, O);
}

// Round 10
// 1293.980 us; speedup vs baseline: 1.0037x; 1.0037x over previous
//
#include <hip/hip_runtime.h>

// BinarizedLinear: act[d,o] = sum_i W[d,o,i] * x[d,i];  out[d,o] = act > bias[d,o]
// W: [D][OUT][IN] fp32 of 0/1   (1.074 GB -- the whole cost; read once, nt, coalesced)
// x: [D][IN] bool               (byte / int32 / float32 storage -- detected on device)
// bias: [D][OUT] fp32
// out: [D][OUT] as float 1.0/0.0 (reference returns bool)
//
// = Round-4 kernel (best measured: nt + front-issued loads) with ONE change:
// the format probe reads one of 16 distinct 256-B windows (wgid%16) instead
// of all 131072 waves hammering the same 4 cache lines of one L2 slice.
// Every window is in-bounds and format-distinguishing under all storage
// candidates (bool>=128KB, int/float>=512KB; misclassify P <= 16*2^-64).
// Sums are exact small integers in fp32 -> reduction order is bit-exact.

#define NDIR 64
#define NOUT 2048
#define NIN  2048

typedef float f4 __attribute__((ext_vector_type(4)));

__global__ __launch_bounds__(256) void binlin_kernel(
    const float* __restrict__ W,
    const unsigned char* __restrict__ X,
    const float* __restrict__ B,
    float* __restrict__ out)
{
    const int lane = threadIdx.x & 63;
    const int wave = threadIdx.x >> 6;                 // 4 waves/block, 1 row/wave
    const int row  = blockIdx.x * 4 + wave;            // [0, NDIR*NOUT)
    const int d    = row >> 11;                        // row / NOUT  (OUT = 2048)

    // --- storage-format probe for X (deterministic, wave-uniform) ---
    // float32: some word == 0x3F800000 (absent w.p. 2^-64 per window).
    // bool bytes: some word > 1 (absent w.p. 8^-64).  int32: all words in {0,1}.
    // Window spread over first 4 KB kills the single-L2-slice hot-spot.
    const unsigned int probe =
        ((const unsigned int*)X)[(row & 15) * 64 + lane];
    const bool x_is_float = (__ballot(probe == 0x3F800000u) != 0ull);
    const bool x_is_bytes = !x_is_float && (__ballot(probe > 1u) != 0ull);

    const f4* w4 = (const f4*)(W + (size_t)row * NIN); // 8 KB row, lane-coalesced float4

    // Issue ALL weight loads first: 8 x global_load_dwordx4 nt, 8 KB in flight.
    f4 w[8];
    #pragma unroll
    for (int j = 0; j < 8; ++j)
        w[j] = __builtin_nontemporal_load(&w4[j * 64 + lane]);

    // Per-lane gate nibble for each float4 (x is L2-hot: reused by 2048 rows).
    unsigned int g[8];
    if (x_is_float) {
        const f4* xf = (const f4*)X + (size_t)d * (NIN / 4);
        #pragma unroll
        for (int j = 0; j < 8; ++j) {
            const f4 xv = xf[j * 64 + lane];
            g[j] = (unsigned)(xv.x != 0.0f)        | ((unsigned)(xv.y != 0.0f) << 1)
                 | ((unsigned)(xv.z != 0.0f) << 2) | ((unsigned)(xv.w != 0.0f) << 3);
        }
    } else if (x_is_bytes) {
        const unsigned int* x4 = (const unsigned int*)(X + (size_t)d * NIN);
        #pragma unroll
        for (int j = 0; j < 8; ++j) {
            const unsigned int xb = x4[j * 64 + lane];   // 4 bool bytes
            g[j] = ((xb & 0x000000ffu) ? 1u : 0u) | ((xb & 0x0000ff00u) ? 2u : 0u)
                 | ((xb & 0x00ff0000u) ? 4u : 0u) | ((xb & 0xff000000u) ? 8u : 0u);
        }
    } else {
        const int* xi = (const int*)X + (size_t)d * NIN;
        #pragma unroll
        for (int j = 0; j < 8; ++j) {
            const int i4 = (j * 64 + lane) * 4;
            g[j] = (xi[i4+0] ? 1u : 0u) | (xi[i4+1] ? 2u : 0u)
                 | (xi[i4+2] ? 4u : 0u) | (xi[i4+3] ? 8u : 0u);
        }
    }

    float acc = 0.0f;
    #pragma unroll
    for (int j = 0; j < 8; ++j) {
        acc += (g[j] & 1u) ? w[j].x : 0.0f;
        acc += (g[j] & 2u) ? w[j].y : 0.0f;
        acc += (g[j] & 4u) ? w[j].z : 0.0f;
        acc += (g[j] & 8u) ? w[j].w : 0.0f;
    }

    // wave-64 reduction; sums are exact small integers in fp32 -> order-independent
    #pragma unroll
    for (int off = 32; off > 0; off >>= 1)
        acc += __shfl_down(acc, off, 64);

    if (lane == 0)
        out[row] = (acc > B[row]) ? 1.0f : 0.0f;
}

extern "C" void kernel_launch(void* const* d_in, const int* in_sizes, int n_in,
                              void* d_out, int out_size, void* d_ws, size_t ws_size,
                              hipStream_t stream) {
    const float*         W = (const float*)d_in[0];
    const unsigned char* X = (const unsigned char*)d_in[1];
    const float*         B = (const float*)d_in[2];
    float*               O = (float*)d_out;

    const int rows = NDIR * NOUT;                      // 131072
    binlin_kernel<<<dim3(rows / 4), dim3(256), 0, stream>>>(W, X, B, O);
}

// Round 12
// 1265.316 us; speedup vs baseline: 1.0264x; 1.0227x over previous
//
#include <hip/hip_runtime.h>

// BinarizedLinear: act[d,o] = sum_i W[d,o,i] * x[d,i];  out[d,o] = act > bias[d,o]
// W: [D][OUT][IN] fp32 of 0/1   (1.074 GB -- the whole cost; read once, nt, coalesced)
// x: [D][IN] bool               (byte / int32 / float32 storage -- detected on device)
// bias: [D][OUT] fp32
// out: [D][OUT] as float 1.0/0.0 (reference returns bool)
//
// Final configuration = Round-4 kernel verbatim (best measured: 1264 us).
// One wave per output row; all 8 nontemporal dwordx4 W loads front-issued
// (8 KB MLP/wave); x-gate nibbles computed while W is in flight; nt keeps
// the 1.074 GB single-use W stream from evicting the L2/L3-resident x/bias.
// Sums are exact small integers in fp32 -> reduction order is bit-exact.

#define NDIR 64
#define NOUT 2048
#define NIN  2048

typedef float f4 __attribute__((ext_vector_type(4)));

__global__ __launch_bounds__(256) void binlin_kernel(
    const float* __restrict__ W,
    const unsigned char* __restrict__ X,
    const float* __restrict__ B,
    float* __restrict__ out)
{
    const int lane = threadIdx.x & 63;
    const int wave = threadIdx.x >> 6;                 // 4 waves/block, 1 row/wave
    const int row  = blockIdx.x * 4 + wave;            // [0, NDIR*NOUT)
    const int d    = row >> 11;                        // row / NOUT  (OUT = 2048)

    // --- storage-format probe for X (deterministic, wave-uniform) ---
    // float32: some word == 0x3F800000 (absent w.p. 2^-64).
    // bool bytes: some word > 1 (absent w.p. 8^-64).  int32: all words in {0,1}.
    const unsigned int probe = ((const unsigned int*)X)[lane];   // 256 B, in-bounds in all layouts
    const bool x_is_float = (__ballot(probe == 0x3F800000u) != 0ull);
    const bool x_is_bytes = !x_is_float && (__ballot(probe > 1u) != 0ull);

    const f4* w4 = (const f4*)(W + (size_t)row * NIN); // 8 KB row, lane-coalesced float4

    // Issue ALL weight loads first: 8 x global_load_dwordx4 nt, 8 KB in flight.
    f4 w[8];
    #pragma unroll
    for (int j = 0; j < 8; ++j)
        w[j] = __builtin_nontemporal_load(&w4[j * 64 + lane]);

    // Per-lane gate nibble for each float4 (x is L2-hot: reused by 2048 rows).
    unsigned int g[8];
    if (x_is_float) {
        const f4* xf = (const f4*)X + (size_t)d * (NIN / 4);
        #pragma unroll
        for (int j = 0; j < 8; ++j) {
            const f4 xv = xf[j * 64 + lane];
            g[j] = (unsigned)(xv.x != 0.0f)        | ((unsigned)(xv.y != 0.0f) << 1)
                 | ((unsigned)(xv.z != 0.0f) << 2) | ((unsigned)(xv.w != 0.0f) << 3);
        }
    } else if (x_is_bytes) {
        const unsigned int* x4 = (const unsigned int*)(X + (size_t)d * NIN);
        #pragma unroll
        for (int j = 0; j < 8; ++j) {
            const unsigned int xb = x4[j * 64 + lane];   // 4 bool bytes
            g[j] = ((xb & 0x000000ffu) ? 1u : 0u) | ((xb & 0x0000ff00u) ? 2u : 0u)
                 | ((xb & 0x00ff0000u) ? 4u : 0u) | ((xb & 0xff000000u) ? 8u : 0u);
        }
    } else {
        const int* xi = (const int*)X + (size_t)d * NIN;
        #pragma unroll
        for (int j = 0; j < 8; ++j) {
            const int i4 = (j * 64 + lane) * 4;
            g[j] = (xi[i4+0] ? 1u : 0u) | (xi[i4+1] ? 2u : 0u)
                 | (xi[i4+2] ? 4u : 0u) | (xi[i4+3] ? 8u : 0u);
        }
    }

    float acc = 0.0f;
    #pragma unroll
    for (int j = 0; j < 8; ++j) {
        acc += (g[j] & 1u) ? w[j].x : 0.0f;
        acc += (g[j] & 2u) ? w[j].y : 0.0f;
        acc += (g[j] & 4u) ? w[j].z : 0.0f;
        acc += (g[j] & 8u) ? w[j].w : 0.0f;
    }

    // wave-64 reduction; sums are exact small integers in fp32 -> order-independent
    #pragma unroll
    for (int off = 32; off > 0; off >>= 1)
        acc += __shfl_down(acc, off, 64);

    if (lane == 0)
        out[row] = (acc > B[row]) ? 1.0f : 0.0f;
}

extern "C" void kernel_launch(void* const* d_in, const int* in_sizes, int n_in,
                              void* d_out, int out_size, void* d_ws, size_t ws_size,
                              hipStream_t stream) {
    const float*         W = (const float*)d_in[0];
    const unsigned char* X = (const unsigned char*)d_in[1];
    const float*         B = (const float*)d_in[2];
    float*               O = (float*)d_out;

    const int rows = NDIR * NOUT;                      // 131072
    binlin_kernel<<<dim3(rows / 4), dim3(256), 0, stream>>>(W, X, B, O);
}